// Round 8
// baseline (385.685 us; speedup 1.0000x reference)
//
#include <hip/hip_runtime.h>
#include <cstdint>

typedef unsigned long long u64;

#define THRESH 0.5f
#define SIGMA 2.0f
#define TPB 64      // pair-tile dim (64x64 pairs per tile)
#define NSPLIT 16   // K splits per tile (1024 words / 16 = 64-word chunks)
#define CST 66      // LDS row stride (u64): <=2-way bank aliasing
#define MAXN 512    // tail capacity (N=500)
#define PCAP 4096   // pair-list capacity (expected ~1.6K matched pairs)

// order-preserving float->uint encode (works for negatives): unsigned compare
// order == float compare order.
__device__ __forceinline__ unsigned encf(float x) {
    unsigned b = __float_as_uint(x);
    return b ^ ((b >> 31) ? 0xFFFFFFFFu : 0x80000000u);
}
__device__ __forceinline__ float decf(unsigned e) {
    unsigned b = (e >> 31) ? (e ^ 0x80000000u) : (e ^ 0xFFFFFFFFu);
    return __uint_as_float(b);
}

struct Tail {
    u64 key[MAXN];               // (score_bits<<32)|(~idx): key[a]>key[b] <=> a precedes b
    float score[MAXN];
    float sum[MAXN];
    int label[MAXN];
    float comp[MAXN];
    unsigned compBits[MAXN];     // atomicMax target (d>=0: uint order == float order)
    unsigned mEnc[MAXN];         // atomicMax target, sign-flip encoded
    unsigned short rank[MAXN];
    unsigned short pb[PCAP];     // pair list: suppressed row
    unsigned short pa[PCAP];     // pair list: suppressor
    float pd[PCAP];              // pair iou
    int pairCnt;
    float gred[4];
    float gmin;
    int isLast;
};                               // ~50 KB

union InterShared {
    u64 sm[2 * TPB][CST];        // 67,584 B popcount staging
    Tail t;
};

// ---------------------------------------------------------------------------
// K1: 4 blocks per mask. Binarize + bit-pack via 64-lane __ballot (fixed
// pixel<->bit bijection identical for all masks -> popcount(AND) exact);
// 4-deep float4 load pipeline; ballot words buffered in wave-private LDS then
// one coalesced 512B store per wave. fp64 partial soft-sums. Zero-fills
// interFull + doneCnt for K2.
// ---------------------------------------------------------------------------
__global__ __launch_bounds__(256) void k_pack(
    const float* __restrict__ preds, u64* __restrict__ packed,
    double* __restrict__ pssum, int* __restrict__ pcnt,
    unsigned* __restrict__ interFull, unsigned* __restrict__ doneCnt,
    int N, int HW)
{
    __shared__ u64 smw[4][64];
    __shared__ double ls[4];
    __shared__ int lc[4];
    const int task = blockIdx.x;
    const int i = task >> 2, sub = task & 3;
    const int seg = HW >> 2;
    const float* src = preds + (size_t)i * HW + (size_t)sub * seg;
    u64* dst = packed + (size_t)i * (HW >> 6) + (size_t)sub * (seg >> 6);
    const int tid = threadIdx.x;
    const int wave = tid >> 6, lane = tid & 63;

    {
        const size_t NN = (size_t)N * N;
        const size_t zbase = (size_t)task * 128;
        for (int z = tid; z < 128; z += 256) {
            const size_t idx = zbase + (size_t)z;
            if (idx < NN) interFull[idx] = 0u;
        }
        if (task == 0 && tid == 0) *doneCnt = 0u;
    }

    const float* wsrc = src + (wave << 12);
    double ssum = 0.0;
    int cnt = 0;
    for (int k = 0; k < 4; ++k) {
        const int base = (k << 10) + (lane << 2);
        float4 v0 = *reinterpret_cast<const float4*>(wsrc + base);
        float4 v1 = *reinterpret_cast<const float4*>(wsrc + base + 256);
        float4 v2 = *reinterpret_cast<const float4*>(wsrc + base + 512);
        float4 v3 = *reinterpret_cast<const float4*>(wsrc + base + 768);
        #pragma unroll
        for (int q = 0; q < 4; ++q) {
            const float4 v = (q == 0) ? v0 : (q == 1) ? v1 : (q == 2) ? v2 : v3;
            const bool b0 = v.x > THRESH, b1 = v.y > THRESH, b2 = v.z > THRESH, b3 = v.w > THRESH;
            const u64 m0 = __ballot(b0);
            const u64 m1 = __ballot(b1);
            const u64 m2 = __ballot(b2);
            const u64 m3 = __ballot(b3);
            if (lane < 4) {
                const u64 m = (lane == 0) ? m0 : (lane == 1) ? m1 : (lane == 2) ? m2 : m3;
                smw[wave][(k << 4) + (q << 2) + lane] = m;
            }
            cnt += (int)b0 + (int)b1 + (int)b2 + (int)b3;
            ssum += (b0 ? (double)v.x : 0.0) + (b1 ? (double)v.y : 0.0)
                  + (b2 ? (double)v.z : 0.0) + (b3 ? (double)v.w : 0.0);
        }
    }
    dst[(wave << 6) + lane] = smw[wave][lane];

    for (int off = 32; off > 0; off >>= 1) {
        ssum += __shfl_down(ssum, off);
        cnt  += __shfl_down(cnt, off);
    }
    if (lane == 0) { ls[wave] = ssum; lc[wave] = cnt; }
    __syncthreads();
    if (tid == 0) {
        pssum[task] = ls[0] + ls[1] + ls[2] + ls[3];
        pcnt[task]  = lc[0] + lc[1] + lc[2] + lc[3];
    }
}

// ---------------------------------------------------------------------------
// K2: pairwise popcount intersections (atomicAdd into dense interFull) +
// elected-last-block tail. Tail is wave-parallel everywhere: no >8-deep
// serial dependent loops.
// ---------------------------------------------------------------------------
__global__ __launch_bounds__(256) void k_inter(
    const u64* __restrict__ packed, unsigned* __restrict__ interFull,
    unsigned* __restrict__ doneCnt,
    const double* __restrict__ pssum, const int* __restrict__ pcnt,
    const float* __restrict__ cate, const int* __restrict__ labels,
    float* __restrict__ out, int N, int WORDS, int NT)
{
    __shared__ InterShared sh;
    const int tid = threadIdx.x;
    const int wave = tid >> 6, lane = tid & 63;

    // ---- popcount phase ----
    {
        int b = blockIdx.x;
        int ti = 0, rowlen = NT;
        while (b >= rowlen) { b -= rowlen; ++ti; --rowlen; }
        const int tj = ti + b;
        const int kwords = WORDS / NSPLIT;
        const int kbase = blockIdx.y * kwords;
        const int a = tid >> 4, bb = tid & 15;

        const int half = kwords >> 1;
        for (int idx = tid; idx < 2 * TPB * half; idx += 256) {
            const int ml = idx / half;
            const int w = (idx - ml * half) << 1;
            const int g = (ml < TPB) ? (ti * TPB + ml) : (tj * TPB + (ml - TPB));
            u64 x0 = 0, x1 = 0;
            if (g < N) {
                const u64* p = packed + (size_t)g * WORDS + kbase + w;
                x0 = p[0];
                x1 = p[1];
            }
            sh.sm[ml][w] = x0;
            sh.sm[ml][w + 1] = x1;
        }
        __syncthreads();

        unsigned acc[4][4] = {};
        #pragma unroll 4
        for (int w = 0; w < kwords; w += 2) {
            u64 pi0[4], pi1[4], pj0[4], pj1[4];
            #pragma unroll
            for (int t = 0; t < 4; ++t) {
                const ulonglong2 q = *reinterpret_cast<const ulonglong2*>(&sh.sm[4 * a + t][w]);
                pi0[t] = q.x; pi1[t] = q.y;
            }
            #pragma unroll
            for (int s = 0; s < 4; ++s) {
                const ulonglong2 q = *reinterpret_cast<const ulonglong2*>(&sh.sm[TPB + bb + 16 * s][w]);
                pj0[s] = q.x; pj1[s] = q.y;
            }
            #pragma unroll
            for (int t = 0; t < 4; ++t)
                #pragma unroll
                for (int s = 0; s < 4; ++s)
                    acc[t][s] += (unsigned)__popcll(pi0[t] & pj0[s])
                               + (unsigned)__popcll(pi1[t] & pj1[s]);
        }
        #pragma unroll
        for (int t = 0; t < 4; ++t)
            #pragma unroll
            for (int s = 0; s < 4; ++s) {
                const int gi = ti * TPB + 4 * a + t;
                const int gj = tj * TPB + bb + 16 * s;
                if (gj < N && gi < gj)
                    atomicAdd(&interFull[(size_t)gi * N + gj], acc[t][s]);
            }
    }

    // ---- last-block election ----
    __syncthreads();
    if (tid == 0) {
        __threadfence();
        const unsigned total = gridDim.x * gridDim.y;
        const unsigned prev = atomicAdd(doneCnt, 1u);
        sh.t.isLast = (prev == total - 1u) ? 1 : 0;
    }
    __syncthreads();
    if (!sh.t.isLast) return;
    __threadfence();

    // ---- T1: finalize scores, init ----
    for (int b = tid; b < MAXN; b += 256) {
        sh.t.key[b] = 0;
        sh.t.compBits[b] = 0;
    }
    if (tid == 0) sh.t.pairCnt = 0;
    __syncthreads();
    for (int b = tid; b < N; b += 256) {
        const double S = ((pssum[4*b] + pssum[4*b+1]) + pssum[4*b+2]) + pssum[4*b+3];
        const int C = ((pcnt[4*b] + pcnt[4*b+1]) + pcnt[4*b+2]) + pcnt[4*b+3];
        const float sc = cate[b] * (float)(S / (double)(C > 1 ? C : 1));
        sh.t.score[b] = sc;
        sh.t.sum[b] = (float)C;
        sh.t.label[b] = labels[b];
        sh.t.key[b] = ((u64)__float_as_uint(sc) << 32) | (u64)(0xFFFFFFFFu - (unsigned)b);
    }
    __syncthreads();

    // ---- T2: wave-per-row rank + matched-pair collection (8-deep lane scan) ----
    for (int b = wave; b < N; b += 4) {
        const u64 kb = sh.t.key[b];
        const int lb = sh.t.label[b];
        int r = 0;
        #pragma unroll
        for (int c0 = 0; c0 < MAXN; c0 += 64) {
            const int a2 = c0 + lane;
            const u64 ka = sh.t.key[a2];            // 0 for a2>=N -> never suppressor
            const bool sup = ka > kb;
            r += (int)sup;
            const bool match = sup && (sh.t.label[a2] == lb);
            if (match) {
                const int slot = atomicAdd(&sh.t.pairCnt, 1);
                if (slot < PCAP) {
                    sh.t.pb[slot] = (unsigned short)b;
                    sh.t.pa[slot] = (unsigned short)a2;
                }
            }
        }
        #pragma unroll
        for (int off = 32; off > 0; off >>= 1) r += __shfl_down(r, off);
        if (lane == 0) sh.t.rank[b] = (unsigned short)r;
    }
    __syncthreads();

    const int PCtot = sh.t.pairCnt;
    if (PCtot <= PCAP) {
        // ---- T3: flat pair fetch (independent parallel global loads) ----
        for (int p = tid; p < PCtot; p += 256) {
            const int b = sh.t.pb[p], a2 = sh.t.pa[p];
            const int lo = a2 < b ? a2 : b, hi = a2 < b ? b : a2;
            const unsigned iv = __hip_atomic_load(&interFull[(size_t)lo * N + hi],
                __ATOMIC_RELAXED, __HIP_MEMORY_SCOPE_AGENT);
            const float inter = (float)iv;
            const float un = sh.t.sum[a2] + sh.t.sum[b] - inter;
            const float d = inter / fmaxf(un, 1.0f);
            sh.t.pd[p] = d;
            atomicMax(&sh.t.compBits[b], __float_as_uint(d));  // d>=0
        }
        __syncthreads();

        // ---- T4a: comp decode + global min ----
        for (int b = tid; b < N; b += 256) sh.t.comp[b] = __uint_as_float(sh.t.compBits[b]);
        __syncthreads();
        float gm = 3.0e38f;
        for (int b = tid; b < N; b += 256) gm = fminf(gm, sh.t.comp[b]);
        #pragma unroll
        for (int off = 32; off > 0; off >>= 1) gm = fminf(gm, __shfl_down(gm, off));
        if (lane == 0) sh.t.gred[wave] = gm;
        __syncthreads();
        if (tid == 0)
            sh.t.gmin = fminf(fminf(sh.t.gred[0], sh.t.gred[1]),
                              fminf(sh.t.gred[2], sh.t.gred[3]));
        __syncthreads();
        const float gmin = sh.t.gmin;

        // ---- T4b: m = max(-gmin^2, per-pair d^2 - comp[a]^2) via encoded atomicMax ----
        const unsigned baseEnc = encf(-(gmin * gmin));
        for (int b = tid; b < N; b += 256) sh.t.mEnc[b] = baseEnc;
        __syncthreads();
        for (int p = tid; p < PCtot; p += 256) {
            const int b = sh.t.pb[p], a2 = sh.t.pa[p];
            const float d = sh.t.pd[p];
            const float ca = sh.t.comp[a2];
            atomicMax(&sh.t.mEnc[b], encf(d * d - ca * ca));
        }
        __syncthreads();

        // ---- T5: decay + scatter by rank ----
        for (int b = tid; b < N; b += 256)
            out[sh.t.rank[b]] = sh.t.score[b] * expf(-SIGMA * decf(sh.t.mEnc[b]));
    } else {
        // ---- overflow fallback: wave-parallel full rescan (rare/never) ----
        for (int b = wave; b < N; b += 4) {
            const u64 kb = sh.t.key[b];
            const int lb = sh.t.label[b];
            const float sub = sh.t.sum[b];
            float cm = 0.0f;
            for (int c0 = 0; c0 < MAXN; c0 += 64) {
                const int a2 = c0 + lane;
                if (sh.t.key[a2] > kb && sh.t.label[a2] == lb) {
                    const int lo = a2 < b ? a2 : b, hi = a2 < b ? b : a2;
                    const unsigned iv = __hip_atomic_load(&interFull[(size_t)lo * N + hi],
                        __ATOMIC_RELAXED, __HIP_MEMORY_SCOPE_AGENT);
                    const float inter = (float)iv;
                    const float un = sh.t.sum[a2] + sub - inter;
                    cm = fmaxf(cm, inter / fmaxf(un, 1.0f));
                }
            }
            #pragma unroll
            for (int off = 32; off > 0; off >>= 1) cm = fmaxf(cm, __shfl_down(cm, off));
            if (lane == 0) sh.t.comp[b] = cm;
        }
        __syncthreads();
        float gm = 3.0e38f;
        for (int b = tid; b < N; b += 256) gm = fminf(gm, sh.t.comp[b]);
        #pragma unroll
        for (int off = 32; off > 0; off >>= 1) gm = fminf(gm, __shfl_down(gm, off));
        if (lane == 0) sh.t.gred[wave] = gm;
        __syncthreads();
        if (tid == 0)
            sh.t.gmin = fminf(fminf(sh.t.gred[0], sh.t.gred[1]),
                              fminf(sh.t.gred[2], sh.t.gred[3]));
        __syncthreads();
        const float gmin = sh.t.gmin;
        for (int b = wave; b < N; b += 4) {
            const u64 kb = sh.t.key[b];
            const int lb = sh.t.label[b];
            const float sub = sh.t.sum[b];
            float m = -(gmin * gmin);
            for (int c0 = 0; c0 < MAXN; c0 += 64) {
                const int a2 = c0 + lane;
                if (sh.t.key[a2] > kb && sh.t.label[a2] == lb) {
                    const int lo = a2 < b ? a2 : b, hi = a2 < b ? b : a2;
                    const unsigned iv = __hip_atomic_load(&interFull[(size_t)lo * N + hi],
                        __ATOMIC_RELAXED, __HIP_MEMORY_SCOPE_AGENT);
                    const float inter = (float)iv;
                    const float un = sh.t.sum[a2] + sub - inter;
                    const float d = inter / fmaxf(un, 1.0f);
                    const float ca = sh.t.comp[a2];
                    m = fmaxf(m, d * d - ca * ca);
                }
            }
            #pragma unroll
            for (int off = 32; off > 0; off >>= 1) m = fmaxf(m, __shfl_down(m, off));
            if (lane == 0) out[sh.t.rank[b]] = sh.t.score[b] * expf(-SIGMA * m);
        }
    }
}

extern "C" void kernel_launch(void* const* d_in, const int* in_sizes, int n_in,
                              void* d_out, int out_size, void* d_ws, size_t ws_size,
                              hipStream_t stream)
{
    const float* preds  = (const float*)d_in[0];
    const float* cate   = (const float*)d_in[1];
    const int*   labels = (const int*)d_in[2];
    float* out = (float*)d_out;

    const int N = in_sizes[1];
    const int HW = in_sizes[0] / N;
    const int WORDS = HW >> 6;

    char* ws = (char*)d_ws;
    size_t off = 0;
    auto take = [&](size_t bytes) -> void* {
        void* p = ws + off;
        off = (off + bytes + 255) & ~(size_t)255;
        return p;
    };
    u64*      packed    = (u64*)     take((size_t)N * WORDS * sizeof(u64));
    double*   pssum     = (double*)  take((size_t)N * 4 * sizeof(double));
    int*      pcnt      = (int*)     take((size_t)N * 4 * sizeof(int));
    unsigned* interFull = (unsigned*)take((size_t)N * N * sizeof(unsigned));
    unsigned* doneCnt   = (unsigned*)take(sizeof(unsigned));
    (void)ws_size; (void)n_in; (void)out_size;

    k_pack<<<N * 4, 256, 0, stream>>>(preds, packed, pssum, pcnt,
                                      interFull, doneCnt, N, HW);

    const int NT = (N + TPB - 1) / TPB;
    dim3 grid(NT * (NT + 1) / 2, NSPLIT);
    k_inter<<<grid, 256, 0, stream>>>(packed, interFull, doneCnt,
                                      pssum, pcnt, cate, labels,
                                      out, N, WORDS, NT);
}